// Round 12
// baseline (501.195 us; speedup 1.0000x reference)
//
#include <hip/hip_runtime.h>
#include <math.h>

namespace {
constexpr int kB = 8;
constexpr int kL = 2048;
constexpr int kD = 512;
constexpr int kTopk = 15;
constexpr int kLMask = 2047;
}

typedef unsigned short u16;
using f32x4 = __attribute__((ext_vector_type(4))) float;
using bf16x8 = __attribute__((ext_vector_type(8))) __bf16;

__device__ __forceinline__ u16 f2b(float f) {
  unsigned u = __float_as_uint(f);
  unsigned r = (u + 0x7fffu + ((u >> 16) & 1u)) >> 16;  // RNE
  return (u16)r;
}
__device__ __forceinline__ float b2f(u16 u) {
  return __uint_as_float(((unsigned)u) << 16);
}

typedef __attribute__((address_space(3))) unsigned int lds_u32;
typedef __attribute__((address_space(1))) const unsigned int glb_u32;
__device__ __forceinline__ void gl2lds16(const void* g, void* l) {
  __builtin_amdgcn_global_load_lds((glb_u32*)g, (lds_u32*)l, 16, 0, 0);
}

// ---------------------------------------------------------------------------
// gemm128: 128x128 tile, BK=64, 256 threads (4 waves 2x2), 32 KiB LDS.
// XOR-swizzled staging source + ds_read, 2-barrier K-loop, coalesced
// LDS-bounce epilogue. RES: 0 none, 1 fp32 ResF, 2 bf16 ResB (split 0).
// ---------------------------------------------------------------------------
template <int SPLITK, int RELU, int HAS_BIAS, int OUTF, int RES>
__global__ __launch_bounds__(256)
void gemm128(const u16* __restrict__ A, const u16* __restrict__ Bt,
             const float* __restrict__ bias, const float* __restrict__ ResF,
             const u16* __restrict__ ResB, u16* __restrict__ outB,
             float* __restrict__ outF, int N, int K, int lda, int ldb, int nbn) {
  __shared__ __align__(16) u16 smu[2][128 * 64];  // As=smu[0], Bs=smu[1]
  u16* As = &smu[0][0];
  u16* Bs = &smu[1][0];

  int lin = blockIdx.x;
  int split = 0;
  const int g2 = SPLITK ? ((int)gridDim.x >> 1) : (int)gridDim.x;
  if (SPLITK && lin >= g2) { split = 1; lin -= g2; }
  const int chunkx = g2 >> 3;                      // g2 % 8 == 0
  const int gid = (lin & 7) * chunkx + (lin >> 3); // bijective XCD swizzle
  const int bm = gid / nbn;
  const int bn = gid - bm * nbn;

  const int tid = threadIdx.x;
  const int wave = tid >> 6;
  const int lane = tid & 63;
  const int ln = lane & 15;
  const int quad = lane >> 4;
  const int wm = (wave >> 1) * 64;
  const int wn = (wave & 1) * 64;

  const int srow = tid >> 3;
  const int schunk = (tid & 7) ^ (srow & 7);

  const size_t koff = (size_t)split * K;  // K = per-split K
  const u16* Ab = A + koff + (size_t)(bm * 128 + srow) * lda + schunk * 8;
  const u16* Bb = Bt + koff + (size_t)(bn * 128 + srow) * ldb + schunk * 8;
  char* ldsA = (char*)As + wave * 1024;
  char* ldsB = (char*)Bs + wave * 1024;

  const int cx0 = ((quad) ^ (ln & 7)) * 8;
  const int cx1 = ((4 | quad) ^ (ln & 7)) * 8;

  f32x4 acc[4][4];
#pragma unroll
  for (int i = 0; i < 4; ++i)
#pragma unroll
    for (int j = 0; j < 4; ++j) acc[i][j] = (f32x4){0.f, 0.f, 0.f, 0.f};

  for (int k0 = 0; k0 < K; k0 += 64) {
#pragma unroll
    for (int c = 0; c < 4; ++c) {
      gl2lds16(Ab + (size_t)(32 * c) * lda + k0, ldsA + c * 4096);
      gl2lds16(Bb + (size_t)(32 * c) * ldb + k0, ldsB + c * 4096);
    }
    __syncthreads();
#pragma unroll
    for (int kk = 0; kk < 2; ++kk) {
      const int cx = kk ? cx1 : cx0;
      bf16x8 af[4], bfr[4];
#pragma unroll
      for (int i = 0; i < 4; ++i)
        af[i] = *(const bf16x8*)(As + (wm + i * 16 + ln) * 64 + cx);
#pragma unroll
      for (int j = 0; j < 4; ++j)
        bfr[j] = *(const bf16x8*)(Bs + (wn + j * 16 + ln) * 64 + cx);
#pragma unroll
      for (int i = 0; i < 4; ++i)
#pragma unroll
        for (int j = 0; j < 4; ++j)
          acc[i][j] = __builtin_amdgcn_mfma_f32_16x16x32_bf16(bfr[j], af[i], acc[i][j], 0, 0, 0);
    }
    __syncthreads();
  }

  const int col0 = bn * 128 + wn + quad * 4;
  const size_t cbase = (size_t)split * ((size_t)16384 * N);
  u16* scr = &smu[0][0];

  if (!OUTF) {
#pragma unroll
    for (int i = 0; i < 4; ++i) {
      const int lr = wm + i * 16 + ln;
      const size_t row = (size_t)(bm * 128 + lr);
#pragma unroll
      for (int j = 0; j < 4; ++j) {
        const int col = col0 + j * 16;
        const int ct = wn + j * 16 + quad * 4;
        f32x4 v = acc[i][j];
        if (HAS_BIAS) {
          float4 bv = *(const float4*)(bias + col);
          v[0] += bv.x; v[1] += bv.y; v[2] += bv.z; v[3] += bv.w;
        }
        if (RES == 1) {
          float4 rv = *(const float4*)(ResF + row * N + col);
          v[0] += rv.x; v[1] += rv.y; v[2] += rv.z; v[3] += rv.w;
        }
        if (RELU) {
          v[0] = fmaxf(v[0], 0.f); v[1] = fmaxf(v[1], 0.f);
          v[2] = fmaxf(v[2], 0.f); v[3] = fmaxf(v[3], 0.f);
        }
        ushort4 o = {f2b(v[0]), f2b(v[1]), f2b(v[2]), f2b(v[3])};
        const int off = (lr * 256 + ct * 2) ^ ((lr & 7) << 4);
        *(ushort4*)((char*)scr + off) = o;
      }
    }
    asm volatile("s_waitcnt lgkmcnt(0)" ::: "memory");
    asm volatile("s_barrier" ::: "memory");
#pragma unroll
    for (int it = 0; it < 8; ++it) {
      const int idx = it * 256 + tid;   // 16B units, 16/row
      const int r = idx >> 4;
      const int u = idx & 15;
      const int src = r * 256 + ((u ^ (r & 7)) << 4);
      f32x4 d = *(const f32x4*)((const char*)scr + src);
      *(f32x4*)((char*)(outB + (size_t)(bm * 128 + r) * N + bn * 128) + u * 16) = d;
    }
  } else {
#pragma unroll
    for (int ch = 0; ch < 2; ++ch) {
      if (ch) {
        asm volatile("s_waitcnt lgkmcnt(0)" ::: "memory");
        asm volatile("s_barrier" ::: "memory");
      }
      if ((wm >> 6) == ch) {
#pragma unroll
        for (int i = 0; i < 4; ++i) {
          const int lr2 = i * 16 + ln;                 // row within chunk
          const size_t row = (size_t)(bm * 128 + ch * 64 + lr2);
#pragma unroll
          for (int j = 0; j < 4; ++j) {
            const int col = col0 + j * 16;
            const int ct = wn + j * 16 + quad * 4;
            f32x4 v = acc[i][j];
            if (HAS_BIAS) {
              float4 bv = *(const float4*)(bias + col);
              v[0] += bv.x; v[1] += bv.y; v[2] += bv.z; v[3] += bv.w;
            }
            if (RES == 2) {
              if (split == 0) {
                ushort4 rv = *(const ushort4*)(ResB + row * N + col);
                v[0] += b2f(rv.x); v[1] += b2f(rv.y); v[2] += b2f(rv.z); v[3] += b2f(rv.w);
              }
            }
            if (RELU) {
              v[0] = fmaxf(v[0], 0.f); v[1] = fmaxf(v[1], 0.f);
              v[2] = fmaxf(v[2], 0.f); v[3] = fmaxf(v[3], 0.f);
            }
            const int off = (lr2 * 512 + ct * 4) ^ ((lr2 & 7) << 4);
            *(f32x4*)((char*)scr + off) = v;
          }
        }
      }
      asm volatile("s_waitcnt lgkmcnt(0)" ::: "memory");
      asm volatile("s_barrier" ::: "memory");
#pragma unroll
      for (int it = 0; it < 8; ++it) {
        const int idx = it * 256 + tid;  // 16B units, 32/row
        const int r = idx >> 5;
        const int u = idx & 31;
        const int src = r * 512 + ((u ^ (r & 7)) << 4);
        f32x4 d = *(const f32x4*)((const char*)scr + src);
        *(f32x4*)(outF + cbase + (size_t)(bm * 128 + ch * 64 + r) * N + bn * 128 + u * 4) = d;
      }
    }
  }
}

// ---------------------------------------------------------------------------
// Fused prep: x cast + weight transposes + bias concat + Asp/Bsp zero-init
// in ONE dispatch. Grid: 8192 | 1024 | 1024 | 1024 | 6 | 17 = 11287 blocks.
// ---------------------------------------------------------------------------
__global__ __launch_bounds__(256)
void prep_kernel(const float* __restrict__ x,
                 const float* __restrict__ Wq, const float* __restrict__ Wk,
                 const float* __restrict__ Wv, const float* __restrict__ Wo,
                 const float* __restrict__ W1, const float* __restrict__ W2,
                 const float* __restrict__ bq, const float* __restrict__ bk,
                 const float* __restrict__ bv,
                 u16* __restrict__ xb, u16* __restrict__ Wqkvt,
                 u16* __restrict__ W1t, u16* __restrict__ W2t,
                 float* __restrict__ bqkv, float* __restrict__ AspBsp) {
  __shared__ float tsh[32][33];
  const int blk = blockIdx.x;
  const int tid = threadIdx.x;
  if (blk < 8192) {                       // x fp32 -> bf16 (8M elems)
    const int i = (blk * 256 + tid) * 4;
    float4 v = *(const float4*)(x + i);
    ushort4 o = {f2b(v.x), f2b(v.y), f2b(v.z), f2b(v.w)};
    *(ushort4*)(xb + i) = o;
  } else if (blk < 9216) {                // Wq/Wk/Wv/Wo [512][512] -> T bf16
    const int rem = blk - 8192;
    const int z = rem >> 8;
    const int by = (rem >> 4) & 15;
    const int bx = rem & 15;
    const float* W = z == 0 ? Wq : z == 1 ? Wk : z == 2 ? Wv : Wo;
    u16* Wt = Wqkvt + (size_t)z * 512 * 512;
    const int k0 = by * 32, n0 = bx * 32;
    const int tx = tid & 31, ty = tid >> 5;
    for (int r = ty; r < 32; r += 8)
      tsh[r][tx] = W[(size_t)(k0 + r) * 512 + n0 + tx];
    __syncthreads();
    for (int r = ty; r < 32; r += 8)
      Wt[(size_t)(n0 + r) * 512 + k0 + tx] = f2b(tsh[tx][r]);
  } else if (blk < 10240) {               // W1 [512][2048] -> W1t [2048][512]
    const int rem = blk - 9216;
    const int bx = rem & 63;
    const int by = rem >> 6;
    const int k0 = by * 32, n0 = bx * 32;
    const int tx = tid & 31, ty = tid >> 5;
    for (int r = ty; r < 32; r += 8)
      tsh[r][tx] = W1[(size_t)(k0 + r) * 2048 + n0 + tx];
    __syncthreads();
    for (int r = ty; r < 32; r += 8)
      W1t[(size_t)(n0 + r) * 512 + k0 + tx] = f2b(tsh[tx][r]);
  } else if (blk < 11264) {               // W2 [2048][512] -> W2t [512][2048]
    const int rem = blk - 10240;
    const int bx = rem & 15;
    const int by = rem >> 4;
    const int k0 = by * 32, n0 = bx * 32;
    const int tx = tid & 31, ty = tid >> 5;
    for (int r = ty; r < 32; r += 8)
      tsh[r][tx] = W2[(size_t)(k0 + r) * 512 + n0 + tx];
    __syncthreads();
    for (int r = ty; r < 32; r += 8)
      W2t[(size_t)(n0 + r) * 2048 + k0 + tx] = f2b(tsh[tx][r]);
  } else if (blk < 11270) {               // bias concat (6 blocks x 256)
    const int i = (blk - 11264) * 256 + tid;
    const float* s = i < 512 ? bq : (i < 1024 ? bk : bv);
    bqkv[i] = s[i & 511];
  } else {                                // zero Asp+Bsp (2*8*1025 floats)
    const int i = (blk - 11270) * 1024 + tid * 4;
    if (i < 16400) {
      AspBsp[i] = 0.f; AspBsp[i + 1] = 0.f;
      AspBsp[i + 2] = 0.f; AspBsp[i + 3] = 0.f;
    }
  }
}

// ---------------------------------------------------------------------------
// Correlation spectra — register radix-8 FFT, register-staged channels.
// Group partials accumulated DIRECTLY into Asp/Bsp via fp32 atomics
// (reduceAB dispatch + 16.8 MB pA/pB round-trip eliminated).
// ---------------------------------------------------------------------------
__global__ __launch_bounds__(256)
void fft_corr(const u16* __restrict__ qkv, float* __restrict__ Asp,
              float* __restrict__ Bsp) {
  __shared__ float re[2048];
  __shared__ float im[2048];
  const int blk = blockIdx.x;
  const int b = blk & 7;
  const int g = blk >> 3;
  const int t = threadIdx.x;
  const float PI = 3.14159265358979323846f;

  const u16* qb = qkv + (size_t)b * kL * 1536 + g * 4;
  ushort4 qv[8], kv[8];
#pragma unroll
  for (int p = 0; p < 8; ++p) {
    const int row = p * 256 + t;
    qv[p] = *(const ushort4*)(qb + (size_t)row * 1536);
    kv[p] = *(const ushort4*)(qb + (size_t)row * 1536 + 512);
  }

  const int r = t & 31;
  float cA[4], sA[4], cB[2], sB[2], cC, sC;   // m=1024,512,256 (index t)
  float cD[4], sD[4], cE[2], sE[2], cF, sF;   // m=128,64,32   (index r)
#pragma unroll
  for (int j = 0; j < 4; ++j)
    __sincosf(PI * (float)(t + 256 * j) * (1.f / 1024.f), &sA[j], &cA[j]);
#pragma unroll
  for (int j = 0; j < 2; ++j)
    __sincosf(PI * (float)(t + 256 * j) * (1.f / 512.f), &sB[j], &cB[j]);
  __sincosf(PI * (float)t * (1.f / 256.f), &sC, &cC);
#pragma unroll
  for (int j = 0; j < 4; ++j)
    __sincosf(PI * (float)(r + 32 * j) * (1.f / 128.f), &sD[j], &cD[j]);
#pragma unroll
  for (int j = 0; j < 2; ++j)
    __sincosf(PI * (float)(r + 32 * j) * (1.f / 64.f), &sE[j], &cE[j]);
  __sincosf(PI * (float)r * (1.f / 32.f), &sF, &cF);
  float sgn[5], cS[5], sS[5];
#pragma unroll
  for (int k = 0; k < 5; ++k) {
    const int m = 16 >> k;
    const bool hi = (t & m) != 0;
    float sv, cv;
    __sincosf(PI * (float)(t & (m - 1)) / (float)m, &sv, &cv);
    sgn[k] = hi ? -1.f : 1.f;
    cS[k] = hi ? cv : 1.f;
    sS[k] = hi ? sv : 0.f;
  }

  float accA[8], accB[8];
#pragma unroll
  for (int i = 0; i < 8; ++i) { accA[i] = 0.f; accB[i] = 0.f; }

  const int base2 = (t >> 5) * 256 + r;

#define BFLY(X, Y, CV, SV)                                              \
  { const float dr_ = er[X] - er[Y], di_ = ei[X] - ei[Y];               \
    er[X] += er[Y]; ei[X] += ei[Y];                                     \
    er[Y] = dr_ * (CV) + di_ * (SV); ei[Y] = di_ * (CV) - dr_ * (SV); }

#pragma unroll
  for (int c = 0; c < 4; ++c) {
    __syncthreads();  // prev channel's unpack reads done before rewrite
    float er[8], ei[8];
#pragma unroll
    for (int j = 0; j < 8; ++j) {
      const u16 qu = (c == 0) ? qv[j].x : (c == 1) ? qv[j].y
                   : (c == 2) ? qv[j].z : qv[j].w;
      const u16 ku = (c == 0) ? kv[j].x : (c == 1) ? kv[j].y
                   : (c == 2) ? kv[j].z : kv[j].w;
      er[j] = b2f(qu);
      ei[j] = b2f(ku);
    }
    BFLY(0, 4, cA[0], sA[0]); BFLY(1, 5, cA[1], sA[1]);
    BFLY(2, 6, cA[2], sA[2]); BFLY(3, 7, cA[3], sA[3]);
    BFLY(0, 2, cB[0], sB[0]); BFLY(1, 3, cB[1], sB[1]);
    BFLY(4, 6, cB[0], sB[0]); BFLY(5, 7, cB[1], sB[1]);
    BFLY(0, 1, cC, sC); BFLY(2, 3, cC, sC);
    BFLY(4, 5, cC, sC); BFLY(6, 7, cC, sC);
#pragma unroll
    for (int j = 0; j < 8; ++j) {
      re[t + 256 * j] = er[j];
      im[t + 256 * j] = ei[j];
    }
    __syncthreads();
#pragma unroll
    for (int j = 0; j < 8; ++j) {
      er[j] = re[base2 + 32 * j];
      ei[j] = im[base2 + 32 * j];
    }
    BFLY(0, 4, cD[0], sD[0]); BFLY(1, 5, cD[1], sD[1]);
    BFLY(2, 6, cD[2], sD[2]); BFLY(3, 7, cD[3], sD[3]);
    BFLY(0, 2, cE[0], sE[0]); BFLY(1, 3, cE[1], sE[1]);
    BFLY(4, 6, cE[0], sE[0]); BFLY(5, 7, cE[1], sE[1]);
    BFLY(0, 1, cF, sF); BFLY(2, 3, cF, sF);
    BFLY(4, 5, cF, sF); BFLY(6, 7, cF, sF);
#pragma unroll
    for (int k = 0; k < 5; ++k) {
      const int m = 16 >> k;
#pragma unroll
      for (int j = 0; j < 8; ++j) {
        const float otr = __shfl_xor(er[j], m, 64);
        const float oti = __shfl_xor(ei[j], m, 64);
        const float sr = otr + sgn[k] * er[j];
        const float si = oti + sgn[k] * ei[j];
        er[j] = sr * cS[k] + si * sS[k];
        ei[j] = si * cS[k] - sr * sS[k];
      }
    }
    __syncthreads();
#pragma unroll
    for (int j = 0; j < 8; ++j) {
      re[base2 + 32 * j] = er[j];
      im[base2 + 32 * j] = ei[j];
    }
    __syncthreads();
#pragma unroll
    for (int i = 0; i < 8; ++i) {
      const int pos = i * 256 + t;
      const int f = __brev((unsigned)pos) >> 21;
      if (f <= 1024) {
        const int fm = (2048 - f) & 2047;
        const int pm = __brev((unsigned)fm) >> 21;
        const float zr = re[pos], zi = im[pos];
        const float mr = re[pm], mi = im[pm];
        const float ReQ = 0.5f * (zr + mr);
        const float ImQ = 0.5f * (zi - mi);
        const float ReK = 0.5f * (zi + mi);
        const float ImK = 0.5f * (mr - zr);
        accA[i] += ReQ * ReK;
        accB[i] += ImQ * ImK;
      }
    }
  }
#undef BFLY

  float* pAb = Asp + b * 1025;
  float* pBb = Bsp + b * 1025;
#pragma unroll
  for (int i = 0; i < 8; ++i) {
    const int pos = i * 256 + t;
    const int f = __brev((unsigned)pos) >> 21;
    if (f <= 1024) {
      atomicAdd(&pAb[f], accA[i]);
      atomicAdd(&pBb[f], accB[i]);
    }
  }
}

// ---------------------------------------------------------------------------
// Fused: inverse FFT (meanv in LDS) + top-15 + softmax. Grid (8 batches).
// ---------------------------------------------------------------------------
__global__ __launch_bounds__(256)
void ifft_topk(const float* __restrict__ Asp, const float* __restrict__ Bsp,
               float* __restrict__ wts, int* __restrict__ dly) {
  __shared__ float re[2048];
  __shared__ float im[2048];
  __shared__ float twc[2047];
  __shared__ float tws[2047];
  __shared__ float rv[256];
  __shared__ int ri[256];
  __shared__ float topv[kTopk];
  __shared__ int topi[kTopk];
  const int b = blockIdx.x;
  const int t = threadIdx.x;
  for (int e = t; e < 2047; e += 256) {
    const int s = 31 - __clz(e + 1);
    const int m = 1 << s;
    const int j = e + 1 - m;
    float sv, cv;
    __sincosf((float)j * 3.14159265358979323846f / (float)m, &sv, &cv);
    twc[e] = cv;
    tws[e] = sv;
  }
#pragma unroll
  for (int i = 0; i < 8; ++i) {
    const int f = i * 256 + t;
    float Xr, Xi;
    if (f <= 1024) {
      Xr = Asp[b * 1025 + f];
      Xi = (f == 0 || f == 1024) ? 0.f : -Bsp[b * 1025 + f];
    } else {
      const int gg = 2048 - f;
      Xr = Asp[b * 1025 + gg];
      Xi = Bsp[b * 1025 + gg];
    }
    const int pos = __brev((unsigned)f) >> 21;
    re[pos] = Xr;
    im[pos] = Xi;
  }
  for (int s = 0; s <= 10; ++s) {
    __syncthreads();
    const int m = 1 << s;
    for (int p = 0; p < 4; ++p) {
      const int id = p * 256 + t;
      const int j = id & (m - 1);
      const int i0 = ((id >> s) << (s + 1)) + j;
      const int i1 = i0 + m;
      const int kk = (m - 1) + j;
      const float cv = twc[kk], sv = tws[kk];
      const float br = re[i1], bi = im[i1];
      const float tr = br * cv - bi * sv;
      const float ti = bi * cv + br * sv;
      const float ar = re[i0], ai = im[i0];
      re[i0] = ar + tr;
      im[i0] = ai + ti;
      re[i1] = ar - tr;
      im[i1] = ai - ti;
    }
  }
  __syncthreads();
#pragma unroll
  for (int i = 0; i < 8; ++i) {
    const int n = i * 256 + t;
    im[n] = re[n] * (1.0f / (2048.0f * 512.0f));
  }
  __syncthreads();
  for (int round = 0; round < kTopk; ++round) {
    float bv = -INFINITY;
    int bi = 0x7fffffff;
#pragma unroll
    for (int i = 0; i < 8; ++i) {
      const int n = i * 256 + t;
      const float v = im[n];
      if (v > bv || (v == bv && n < bi)) { bv = v; bi = n; }
    }
    rv[t] = bv;
    ri[t] = bi;
    __syncthreads();
    for (int s = 128; s > 0; s >>= 1) {
      if (t < s) {
        const float v2 = rv[t + s];
        const int i2 = ri[t + s];
        if (v2 > rv[t] || (v2 == rv[t] && i2 < ri[t])) { rv[t] = v2; ri[t] = i2; }
      }
      __syncthreads();
    }
    if (t == 0) {
      topv[round] = rv[0];
      topi[round] = ri[0];
      im[ri[0]] = -INFINITY;
    }
    __syncthreads();
  }
  if (t == 0) {
    const float m = topv[0];
    float sum = 0.f;
    float e[kTopk];
    for (int i = 0; i < kTopk; ++i) { e[i] = expf(topv[i] - m); sum += e[i]; }
    for (int i = 0; i < kTopk; ++i) {
      wts[b * 16 + i] = e[i] / sum;
      dly[b * 16 + i] = topi[i];
    }
  }
}

// attn_in[b,l,c] = sum_t w_t * v[b,(l+delay_t)%L,c]; 1-D grid, batch = lin%8
__global__ __launch_bounds__(256)
void agg_kernel(const u16* __restrict__ qkv, const float* __restrict__ wts,
                const int* __restrict__ dly, u16* __restrict__ out) {
  __shared__ float w[16];
  __shared__ int dl[16];
  const int lin = blockIdx.x;
  const int b = lin & 7;
  if (threadIdx.x < kTopk) {
    w[threadIdx.x] = wts[b * 16 + threadIdx.x];
    dl[threadIdx.x] = dly[b * 16 + threadIdx.x];
  }
  __syncthreads();
  const int l = (lin >> 3) * 4 + (threadIdx.x >> 6);
  const int co = (threadIdx.x & 63) * 8;
  const u16* vb = qkv + (size_t)b * kL * 1536 + 1024 + co;
  float a[8] = {0.f, 0.f, 0.f, 0.f, 0.f, 0.f, 0.f, 0.f};
  for (int t = 0; t < kTopk; ++t) {
    const int row = (l + dl[t]) & kLMask;
    float4 rv = *(const float4*)(vb + (size_t)row * 1536);
    const u16* p = (const u16*)&rv;
    const float wt = w[t];
#pragma unroll
    for (int e = 0; e < 8; ++e) a[e] += wt * b2f(p[e]);
  }
  u16 ob[8];
#pragma unroll
  for (int e = 0; e < 8; ++e) ob[e] = f2b(a[e]);
  *(float4*)(out + ((size_t)b * kL + l) * kD + co) = *(const float4*)ob;
}

// decomp, bf16 in -> bf16 out (streaming 25-tap clamped MA)
__global__ __launch_bounds__(256)
void decomp_b2b(const u16* __restrict__ X, u16* __restrict__ OB) {
  const int c = blockIdx.x * 256 + threadIdx.x;
  const int b = blockIdx.y;
  const int l0 = blockIdx.z * 64;
  const u16* base = X + (size_t)b * kL * kD + c;
  float sum = 0.f;
#pragma unroll
  for (int m = -12; m <= 12; ++m) {
    int lm = l0 + m;
    lm = lm < 0 ? 0 : (lm > kL - 1 ? kL - 1 : lm);
    sum += b2f(base[(size_t)lm * kD]);
  }
#pragma unroll 4
  for (int l = l0; l < l0 + 64; ++l) {
    const float val = b2f(base[(size_t)l * kD]);
    OB[((size_t)b * kL + l) * kD + c] = f2b(val - sum * (1.0f / 25.0f));
    const int la = l + 13 > kL - 1 ? kL - 1 : l + 13;
    const int lr = l - 12 < 0 ? 0 : l - 12;
    sum += b2f(base[(size_t)la * kD]) - b2f(base[(size_t)lr * kD]);
  }
}

// decomp, fp32 in -> fp32 out (single input; FFN2 writes the full sum)
__global__ __launch_bounds__(256)
void decomp_f2f(const float* __restrict__ X, float* __restrict__ OF) {
  const int c = blockIdx.x * 256 + threadIdx.x;
  const int b = blockIdx.y;
  const int l0 = blockIdx.z * 64;
  const float* base = X + (size_t)b * kL * kD + c;
  float sum = 0.f;
#pragma unroll
  for (int m = -12; m <= 12; ++m) {
    int lm = l0 + m;
    lm = lm < 0 ? 0 : (lm > kL - 1 ? kL - 1 : lm);
    sum += base[(size_t)lm * kD];
  }
#pragma unroll 4
  for (int l = l0; l < l0 + 64; ++l) {
    const float val = base[(size_t)l * kD];
    OF[((size_t)b * kL + l) * kD + c] = val - sum * (1.0f / 25.0f);
    const int la = l + 13 > kL - 1 ? kL - 1 : l + 13;
    const int lr = l - 12 < 0 ? 0 : l - 12;
    sum += base[(size_t)la * kD] - base[(size_t)lr * kD];
  }
}

extern "C" void kernel_launch(void* const* d_in, const int* in_sizes, int n_in,
                              void* d_out, int out_size, void* d_ws, size_t ws_size,
                              hipStream_t stream) {
  const float* x  = (const float*)d_in[0];
  const float* Wq = (const float*)d_in[1];
  const float* bq = (const float*)d_in[2];
  const float* Wk = (const float*)d_in[3];
  const float* bk = (const float*)d_in[4];
  const float* Wv = (const float*)d_in[5];
  const float* bv = (const float*)d_in[6];
  const float* Wo = (const float*)d_in[7];
  const float* bo = (const float*)d_in[8];
  const float* W1 = (const float*)d_in[9];
  const float* W2 = (const float*)d_in[10];
  float* out = (float*)d_out;

  const size_t MiB = 1u << 20;
  const size_t NBLD = (size_t)kB * kL * kD;  // 8,388,608
  char* base = (char*)d_ws;
  u16*   qkvb  = (u16*)(base);               // [0,48)
  u16*   xb    = (u16*)(base + 48 * MiB);    // [48,64) ; aggb aliases
  u16*   aggb  = xb;
  u16*   xrb   = (u16*)(base + 64 * MiB);    // [64,80)
  u16*   s1b   = (u16*)(base + 80 * MiB);    // [80,96)
  u16*   midb  = (u16*)(base + 96 * MiB);    // [96,160)
  float* s2p   = (float*)(base);             // [0,64) after qkvb/aggb dead
  u16*   Wqkvt = (u16*)(base + 160 * MiB);   // 2 MiB (incl Wot as slot 3)
  u16*   Wot   = Wqkvt + 3 * 512 * 512;
  u16*   W1t   = (u16*)(base + 162 * MiB);   // 2 MiB
  u16*   W2t   = (u16*)(base + 164 * MiB);   // 2 MiB
  float* bqkv  = (float*)(base + 166 * MiB);
  float* Asp   = bqkv + 2048;                // 8 x 1025
  float* Bsp   = Asp + kB * 1025;
  float* wtsf  = Bsp + kB * 1025;
  int*   dlyi  = (int*)(wtsf + kB * 16);

  const dim3 blk(256);

  // fused input cast + weight prep + bias concat + Asp/Bsp zero (one dispatch)
  prep_kernel<<<dim3(11287), blk, 0, stream>>>(
      x, Wq, Wk, Wv, Wo, W1, W2, bq, bk, bv, xb, Wqkvt, W1t, W2t, bqkv, Asp);

  // fused QKV projection -> qkvb bf16 (128^2 tiles, 128x12 = 1536 blocks)
  gemm128<0, 0, 1, 0, 0><<<dim3(1536), blk, 0, stream>>>(
      xb, Wqkvt, bqkv, nullptr, nullptr, qkvb, nullptr, 1536, 512, 512, 512, 12);

  // correlation spectra (atomic-accumulated into Asp/Bsp) + topk
  fft_corr<<<dim3(1024), blk, 0, stream>>>(qkvb, Asp, Bsp);
  ifft_topk<<<dim3(8), blk, 0, stream>>>(Asp, Bsp, wtsf, dlyi);

  // delay aggregation -> aggb bf16 ; Wo + bias + residual(x) -> xrb bf16
  agg_kernel<<<dim3(4096), blk, 0, stream>>>(qkvb, wtsf, dlyi, aggb);
  gemm128<0, 0, 1, 0, 1><<<dim3(512), blk, 0, stream>>>(
      aggb, Wot, bo, x, nullptr, xrb, nullptr, 512, 512, 512, 512, 4);

  // decomp 1 -> s1b bf16
  decomp_b2b<<<dim3(2, 8, 32), blk, 0, stream>>>(xrb, s1b);

  // FFN1: relu(s1b @ W1) -> midb bf16 (128x16 = 2048 blocks)
  gemm128<0, 1, 0, 0, 0><<<dim3(2048), blk, 0, stream>>>(
      s1b, W1t, nullptr, nullptr, nullptr, midb, nullptr, 2048, 512, 512, 512, 16);

  // FFN2: full K=2048, no split (512 blocks, NT=32) -> s2p fp32 + s1b residual
  gemm128<0, 0, 0, 1, 2><<<dim3(512), blk, 0, stream>>>(
      midb, W2t, nullptr, nullptr, s1b, nullptr, s2p, 512, 2048, 2048, 2048, 4);

  // decomp 2 over s2p -> out fp32
  decomp_f2f<<<dim3(2, 8, 32), blk, 0, stream>>>(s2p, out);
}

// Round 13
// 369.180 us; speedup vs baseline: 1.3576x; 1.3576x over previous
//
#include <hip/hip_runtime.h>
#include <math.h>

namespace {
constexpr int kB = 8;
constexpr int kL = 2048;
constexpr int kD = 512;
constexpr int kTopk = 15;
constexpr int kLMask = 2047;
}

typedef unsigned short u16;
using f32x4 = __attribute__((ext_vector_type(4))) float;
using bf16x8 = __attribute__((ext_vector_type(8))) __bf16;

__device__ __forceinline__ u16 f2b(float f) {
  unsigned u = __float_as_uint(f);
  unsigned r = (u + 0x7fffu + ((u >> 16) & 1u)) >> 16;  // RNE
  return (u16)r;
}
__device__ __forceinline__ float b2f(u16 u) {
  return __uint_as_float(((unsigned)u) << 16);
}

typedef __attribute__((address_space(3))) unsigned int lds_u32;
typedef __attribute__((address_space(1))) const unsigned int glb_u32;
__device__ __forceinline__ void gl2lds16(const void* g, void* l) {
  __builtin_amdgcn_global_load_lds((glb_u32*)g, (lds_u32*)l, 16, 0, 0);
}

// ---------------------------------------------------------------------------
// gemm128: 128x128 tile, BK=64, 256 threads (4 waves 2x2), 32 KiB LDS.
// XOR-swizzled staging source + ds_read, 2-barrier K-loop, coalesced
// LDS-bounce epilogue. RES: 0 none, 1 fp32 ResF, 2 bf16 ResB (split 0).
// ---------------------------------------------------------------------------
template <int SPLITK, int RELU, int HAS_BIAS, int OUTF, int RES>
__global__ __launch_bounds__(256)
void gemm128(const u16* __restrict__ A, const u16* __restrict__ Bt,
             const float* __restrict__ bias, const float* __restrict__ ResF,
             const u16* __restrict__ ResB, u16* __restrict__ outB,
             float* __restrict__ outF, int N, int K, int lda, int ldb, int nbn) {
  __shared__ __align__(16) u16 smu[2][128 * 64];  // As=smu[0], Bs=smu[1]
  u16* As = &smu[0][0];
  u16* Bs = &smu[1][0];

  int lin = blockIdx.x;
  int split = 0;
  const int g2 = SPLITK ? ((int)gridDim.x >> 1) : (int)gridDim.x;
  if (SPLITK && lin >= g2) { split = 1; lin -= g2; }
  const int chunkx = g2 >> 3;                      // g2 % 8 == 0
  const int gid = (lin & 7) * chunkx + (lin >> 3); // bijective XCD swizzle
  const int bm = gid / nbn;
  const int bn = gid - bm * nbn;

  const int tid = threadIdx.x;
  const int wave = tid >> 6;
  const int lane = tid & 63;
  const int ln = lane & 15;
  const int quad = lane >> 4;
  const int wm = (wave >> 1) * 64;
  const int wn = (wave & 1) * 64;

  const int srow = tid >> 3;
  const int schunk = (tid & 7) ^ (srow & 7);

  const size_t koff = (size_t)split * K;  // K = per-split K
  const u16* Ab = A + koff + (size_t)(bm * 128 + srow) * lda + schunk * 8;
  const u16* Bb = Bt + koff + (size_t)(bn * 128 + srow) * ldb + schunk * 8;
  char* ldsA = (char*)As + wave * 1024;
  char* ldsB = (char*)Bs + wave * 1024;

  const int cx0 = ((quad) ^ (ln & 7)) * 8;
  const int cx1 = ((4 | quad) ^ (ln & 7)) * 8;

  f32x4 acc[4][4];
#pragma unroll
  for (int i = 0; i < 4; ++i)
#pragma unroll
    for (int j = 0; j < 4; ++j) acc[i][j] = (f32x4){0.f, 0.f, 0.f, 0.f};

  for (int k0 = 0; k0 < K; k0 += 64) {
#pragma unroll
    for (int c = 0; c < 4; ++c) {
      gl2lds16(Ab + (size_t)(32 * c) * lda + k0, ldsA + c * 4096);
      gl2lds16(Bb + (size_t)(32 * c) * ldb + k0, ldsB + c * 4096);
    }
    __syncthreads();
#pragma unroll
    for (int kk = 0; kk < 2; ++kk) {
      const int cx = kk ? cx1 : cx0;
      bf16x8 af[4], bfr[4];
#pragma unroll
      for (int i = 0; i < 4; ++i)
        af[i] = *(const bf16x8*)(As + (wm + i * 16 + ln) * 64 + cx);
#pragma unroll
      for (int j = 0; j < 4; ++j)
        bfr[j] = *(const bf16x8*)(Bs + (wn + j * 16 + ln) * 64 + cx);
#pragma unroll
      for (int i = 0; i < 4; ++i)
#pragma unroll
        for (int j = 0; j < 4; ++j)
          acc[i][j] = __builtin_amdgcn_mfma_f32_16x16x32_bf16(bfr[j], af[i], acc[i][j], 0, 0, 0);
    }
    __syncthreads();
  }

  const int col0 = bn * 128 + wn + quad * 4;
  const size_t cbase = (size_t)split * ((size_t)16384 * N);
  u16* scr = &smu[0][0];

  if (!OUTF) {
#pragma unroll
    for (int i = 0; i < 4; ++i) {
      const int lr = wm + i * 16 + ln;
      const size_t row = (size_t)(bm * 128 + lr);
#pragma unroll
      for (int j = 0; j < 4; ++j) {
        const int col = col0 + j * 16;
        const int ct = wn + j * 16 + quad * 4;
        f32x4 v = acc[i][j];
        if (HAS_BIAS) {
          float4 bv = *(const float4*)(bias + col);
          v[0] += bv.x; v[1] += bv.y; v[2] += bv.z; v[3] += bv.w;
        }
        if (RES == 1) {
          float4 rv = *(const float4*)(ResF + row * N + col);
          v[0] += rv.x; v[1] += rv.y; v[2] += rv.z; v[3] += rv.w;
        }
        if (RELU) {
          v[0] = fmaxf(v[0], 0.f); v[1] = fmaxf(v[1], 0.f);
          v[2] = fmaxf(v[2], 0.f); v[3] = fmaxf(v[3], 0.f);
        }
        ushort4 o = {f2b(v[0]), f2b(v[1]), f2b(v[2]), f2b(v[3])};
        const int off = (lr * 256 + ct * 2) ^ ((lr & 7) << 4);
        *(ushort4*)((char*)scr + off) = o;
      }
    }
    asm volatile("s_waitcnt lgkmcnt(0)" ::: "memory");
    asm volatile("s_barrier" ::: "memory");
#pragma unroll
    for (int it = 0; it < 8; ++it) {
      const int idx = it * 256 + tid;   // 16B units, 16/row
      const int r = idx >> 4;
      const int u = idx & 15;
      const int src = r * 256 + ((u ^ (r & 7)) << 4);
      f32x4 d = *(const f32x4*)((const char*)scr + src);
      *(f32x4*)((char*)(outB + (size_t)(bm * 128 + r) * N + bn * 128) + u * 16) = d;
    }
  } else {
#pragma unroll
    for (int ch = 0; ch < 2; ++ch) {
      if (ch) {
        asm volatile("s_waitcnt lgkmcnt(0)" ::: "memory");
        asm volatile("s_barrier" ::: "memory");
      }
      if ((wm >> 6) == ch) {
#pragma unroll
        for (int i = 0; i < 4; ++i) {
          const int lr2 = i * 16 + ln;                 // row within chunk
          const size_t row = (size_t)(bm * 128 + ch * 64 + lr2);
#pragma unroll
          for (int j = 0; j < 4; ++j) {
            const int col = col0 + j * 16;
            const int ct = wn + j * 16 + quad * 4;
            f32x4 v = acc[i][j];
            if (HAS_BIAS) {
              float4 bv = *(const float4*)(bias + col);
              v[0] += bv.x; v[1] += bv.y; v[2] += bv.z; v[3] += bv.w;
            }
            if (RES == 2) {
              if (split == 0) {
                ushort4 rv = *(const ushort4*)(ResB + row * N + col);
                v[0] += b2f(rv.x); v[1] += b2f(rv.y); v[2] += b2f(rv.z); v[3] += b2f(rv.w);
              }
            }
            if (RELU) {
              v[0] = fmaxf(v[0], 0.f); v[1] = fmaxf(v[1], 0.f);
              v[2] = fmaxf(v[2], 0.f); v[3] = fmaxf(v[3], 0.f);
            }
            const int off = (lr2 * 512 + ct * 4) ^ ((lr2 & 7) << 4);
            *(f32x4*)((char*)scr + off) = v;
          }
        }
      }
      asm volatile("s_waitcnt lgkmcnt(0)" ::: "memory");
      asm volatile("s_barrier" ::: "memory");
#pragma unroll
      for (int it = 0; it < 8; ++it) {
        const int idx = it * 256 + tid;  // 16B units, 32/row
        const int r = idx >> 5;
        const int u = idx & 31;
        const int src = r * 512 + ((u ^ (r & 7)) << 4);
        f32x4 d = *(const f32x4*)((const char*)scr + src);
        *(f32x4*)(outF + cbase + (size_t)(bm * 128 + ch * 64 + r) * N + bn * 128 + u * 4) = d;
      }
    }
  }
}

// ---------------------------------------------------------------------------
// Fused prep: x cast + weight transposes + bias concat in ONE dispatch.
// ---------------------------------------------------------------------------
__global__ __launch_bounds__(256)
void prep_kernel(const float* __restrict__ x,
                 const float* __restrict__ Wq, const float* __restrict__ Wk,
                 const float* __restrict__ Wv, const float* __restrict__ Wo,
                 const float* __restrict__ W1, const float* __restrict__ W2,
                 const float* __restrict__ bq, const float* __restrict__ bk,
                 const float* __restrict__ bv,
                 u16* __restrict__ xb, u16* __restrict__ Wqkvt,
                 u16* __restrict__ W1t, u16* __restrict__ W2t,
                 float* __restrict__ bqkv) {
  __shared__ float tsh[32][33];
  const int blk = blockIdx.x;
  const int tid = threadIdx.x;
  if (blk < 8192) {                       // x fp32 -> bf16 (8M elems)
    const int i = (blk * 256 + tid) * 4;
    float4 v = *(const float4*)(x + i);
    ushort4 o = {f2b(v.x), f2b(v.y), f2b(v.z), f2b(v.w)};
    *(ushort4*)(xb + i) = o;
  } else if (blk < 9216) {                // Wq/Wk/Wv/Wo [512][512] -> T bf16
    const int rem = blk - 8192;
    const int z = rem >> 8;
    const int by = (rem >> 4) & 15;
    const int bx = rem & 15;
    const float* W = z == 0 ? Wq : z == 1 ? Wk : z == 2 ? Wv : Wo;
    u16* Wt = Wqkvt + (size_t)z * 512 * 512;
    const int k0 = by * 32, n0 = bx * 32;
    const int tx = tid & 31, ty = tid >> 5;
    for (int r = ty; r < 32; r += 8)
      tsh[r][tx] = W[(size_t)(k0 + r) * 512 + n0 + tx];
    __syncthreads();
    for (int r = ty; r < 32; r += 8)
      Wt[(size_t)(n0 + r) * 512 + k0 + tx] = f2b(tsh[tx][r]);
  } else if (blk < 10240) {               // W1 [512][2048] -> W1t [2048][512]
    const int rem = blk - 9216;
    const int bx = rem & 63;
    const int by = rem >> 6;
    const int k0 = by * 32, n0 = bx * 32;
    const int tx = tid & 31, ty = tid >> 5;
    for (int r = ty; r < 32; r += 8)
      tsh[r][tx] = W1[(size_t)(k0 + r) * 2048 + n0 + tx];
    __syncthreads();
    for (int r = ty; r < 32; r += 8)
      W1t[(size_t)(n0 + r) * 512 + k0 + tx] = f2b(tsh[tx][r]);
  } else if (blk < 11264) {               // W2 [2048][512] -> W2t [512][2048]
    const int rem = blk - 10240;
    const int bx = rem & 15;
    const int by = rem >> 4;
    const int k0 = by * 32, n0 = bx * 32;
    const int tx = tid & 31, ty = tid >> 5;
    for (int r = ty; r < 32; r += 8)
      tsh[r][tx] = W2[(size_t)(k0 + r) * 512 + n0 + tx];
    __syncthreads();
    for (int r = ty; r < 32; r += 8)
      W2t[(size_t)(n0 + r) * 2048 + k0 + tx] = f2b(tsh[tx][r]);
  } else {                                // bias concat (6 blocks x 256)
    const int i = (blk - 11264) * 256 + tid;
    const float* s = i < 512 ? bq : (i < 1024 ? bk : bv);
    bqkv[i] = s[i & 511];
  }
}

// ---------------------------------------------------------------------------
// Correlation spectra — register radix-8 FFT, register-staged channels.
// ---------------------------------------------------------------------------
__global__ __launch_bounds__(256)
void fft_corr(const u16* __restrict__ qkv, float* __restrict__ pA,
              float* __restrict__ pB) {
  __shared__ float re[2048];
  __shared__ float im[2048];
  const int blk = blockIdx.x;
  const int b = blk & 7;
  const int g = blk >> 3;
  const int t = threadIdx.x;
  const float PI = 3.14159265358979323846f;

  const u16* qb = qkv + (size_t)b * kL * 1536 + g * 4;
  ushort4 qv[8], kv[8];
#pragma unroll
  for (int p = 0; p < 8; ++p) {
    const int row = p * 256 + t;
    qv[p] = *(const ushort4*)(qb + (size_t)row * 1536);
    kv[p] = *(const ushort4*)(qb + (size_t)row * 1536 + 512);
  }

  const int r = t & 31;
  float cA[4], sA[4], cB[2], sB[2], cC, sC;   // m=1024,512,256 (index t)
  float cD[4], sD[4], cE[2], sE[2], cF, sF;   // m=128,64,32   (index r)
#pragma unroll
  for (int j = 0; j < 4; ++j)
    __sincosf(PI * (float)(t + 256 * j) * (1.f / 1024.f), &sA[j], &cA[j]);
#pragma unroll
  for (int j = 0; j < 2; ++j)
    __sincosf(PI * (float)(t + 256 * j) * (1.f / 512.f), &sB[j], &cB[j]);
  __sincosf(PI * (float)t * (1.f / 256.f), &sC, &cC);
#pragma unroll
  for (int j = 0; j < 4; ++j)
    __sincosf(PI * (float)(r + 32 * j) * (1.f / 128.f), &sD[j], &cD[j]);
#pragma unroll
  for (int j = 0; j < 2; ++j)
    __sincosf(PI * (float)(r + 32 * j) * (1.f / 64.f), &sE[j], &cE[j]);
  __sincosf(PI * (float)r * (1.f / 32.f), &sF, &cF);
  float sgn[5], cS[5], sS[5];
#pragma unroll
  for (int k = 0; k < 5; ++k) {
    const int m = 16 >> k;
    const bool hi = (t & m) != 0;
    float sv, cv;
    __sincosf(PI * (float)(t & (m - 1)) / (float)m, &sv, &cv);
    sgn[k] = hi ? -1.f : 1.f;
    cS[k] = hi ? cv : 1.f;
    sS[k] = hi ? sv : 0.f;
  }

  float accA[8], accB[8];
#pragma unroll
  for (int i = 0; i < 8; ++i) { accA[i] = 0.f; accB[i] = 0.f; }

  const int base2 = (t >> 5) * 256 + r;

#define BFLY(X, Y, CV, SV)                                              \
  { const float dr_ = er[X] - er[Y], di_ = ei[X] - ei[Y];               \
    er[X] += er[Y]; ei[X] += ei[Y];                                     \
    er[Y] = dr_ * (CV) + di_ * (SV); ei[Y] = di_ * (CV) - dr_ * (SV); }

#pragma unroll
  for (int c = 0; c < 4; ++c) {
    __syncthreads();  // prev channel's unpack reads done before rewrite
    float er[8], ei[8];
#pragma unroll
    for (int j = 0; j < 8; ++j) {
      const u16 qu = (c == 0) ? qv[j].x : (c == 1) ? qv[j].y
                   : (c == 2) ? qv[j].z : qv[j].w;
      const u16 ku = (c == 0) ? kv[j].x : (c == 1) ? kv[j].y
                   : (c == 2) ? kv[j].z : kv[j].w;
      er[j] = b2f(qu);
      ei[j] = b2f(ku);
    }
    BFLY(0, 4, cA[0], sA[0]); BFLY(1, 5, cA[1], sA[1]);
    BFLY(2, 6, cA[2], sA[2]); BFLY(3, 7, cA[3], sA[3]);
    BFLY(0, 2, cB[0], sB[0]); BFLY(1, 3, cB[1], sB[1]);
    BFLY(4, 6, cB[0], sB[0]); BFLY(5, 7, cB[1], sB[1]);
    BFLY(0, 1, cC, sC); BFLY(2, 3, cC, sC);
    BFLY(4, 5, cC, sC); BFLY(6, 7, cC, sC);
#pragma unroll
    for (int j = 0; j < 8; ++j) {
      re[t + 256 * j] = er[j];
      im[t + 256 * j] = ei[j];
    }
    __syncthreads();
#pragma unroll
    for (int j = 0; j < 8; ++j) {
      er[j] = re[base2 + 32 * j];
      ei[j] = im[base2 + 32 * j];
    }
    BFLY(0, 4, cD[0], sD[0]); BFLY(1, 5, cD[1], sD[1]);
    BFLY(2, 6, cD[2], sD[2]); BFLY(3, 7, cD[3], sD[3]);
    BFLY(0, 2, cE[0], sE[0]); BFLY(1, 3, cE[1], sE[1]);
    BFLY(4, 6, cE[0], sE[0]); BFLY(5, 7, cE[1], sE[1]);
    BFLY(0, 1, cF, sF); BFLY(2, 3, cF, sF);
    BFLY(4, 5, cF, sF); BFLY(6, 7, cF, sF);
#pragma unroll
    for (int k = 0; k < 5; ++k) {
      const int m = 16 >> k;
#pragma unroll
      for (int j = 0; j < 8; ++j) {
        const float otr = __shfl_xor(er[j], m, 64);
        const float oti = __shfl_xor(ei[j], m, 64);
        const float sr = otr + sgn[k] * er[j];
        const float si = oti + sgn[k] * ei[j];
        er[j] = sr * cS[k] + si * sS[k];
        ei[j] = si * cS[k] - sr * sS[k];
      }
    }
    __syncthreads();
#pragma unroll
    for (int j = 0; j < 8; ++j) {
      re[base2 + 32 * j] = er[j];
      im[base2 + 32 * j] = ei[j];
    }
    __syncthreads();
#pragma unroll
    for (int i = 0; i < 8; ++i) {
      const int pos = i * 256 + t;
      const int f = __brev((unsigned)pos) >> 21;
      if (f <= 1024) {
        const int fm = (2048 - f) & 2047;
        const int pm = __brev((unsigned)fm) >> 21;
        const float zr = re[pos], zi = im[pos];
        const float mr = re[pm], mi = im[pm];
        const float ReQ = 0.5f * (zr + mr);
        const float ImQ = 0.5f * (zi - mi);
        const float ReK = 0.5f * (zi + mi);
        const float ImK = 0.5f * (mr - zr);
        accA[i] += ReQ * ReK;
        accB[i] += ImQ * ImK;
      }
    }
  }
#undef BFLY

  float* pAb = pA + (size_t)blk * 1025;
  float* pBb = pB + (size_t)blk * 1025;
#pragma unroll
  for (int i = 0; i < 8; ++i) {
    const int pos = i * 256 + t;
    const int f = __brev((unsigned)pos) >> 21;
    if (f <= 1024) { pAb[f] = accA[i]; pBb[f] = accB[i]; }
  }
}

// sum 128 group partials -> Asp/Bsp. Grid (8 batches, 5 freq chunks).
__global__ __launch_bounds__(256)
void reduceAB(const float* __restrict__ pA, const float* __restrict__ pB,
              float* __restrict__ Asp, float* __restrict__ Bsp) {
  const int b = blockIdx.x;
  const int f = blockIdx.y * 256 + threadIdx.x;
  if (f > 1024) return;
  float sa = 0.f, sb = 0.f;
  for (int g = 0; g < 128; ++g) {
    const size_t idx = (size_t)((g << 3) | b) * 1025 + f;
    sa += pA[idx];
    sb += pB[idx];
  }
  Asp[b * 1025 + f] = sa;
  Bsp[b * 1025 + f] = sb;
}

// ---------------------------------------------------------------------------
// Fused: inverse FFT (meanv in LDS) + top-15 + softmax. Grid (8 batches).
// ---------------------------------------------------------------------------
__global__ __launch_bounds__(256)
void ifft_topk(const float* __restrict__ Asp, const float* __restrict__ Bsp,
               float* __restrict__ wts, int* __restrict__ dly) {
  __shared__ float re[2048];
  __shared__ float im[2048];
  __shared__ float twc[2047];
  __shared__ float tws[2047];
  __shared__ float rv[256];
  __shared__ int ri[256];
  __shared__ float topv[kTopk];
  __shared__ int topi[kTopk];
  const int b = blockIdx.x;
  const int t = threadIdx.x;
  for (int e = t; e < 2047; e += 256) {
    const int s = 31 - __clz(e + 1);
    const int m = 1 << s;
    const int j = e + 1 - m;
    float sv, cv;
    __sincosf((float)j * 3.14159265358979323846f / (float)m, &sv, &cv);
    twc[e] = cv;
    tws[e] = sv;
  }
#pragma unroll
  for (int i = 0; i < 8; ++i) {
    const int f = i * 256 + t;
    float Xr, Xi;
    if (f <= 1024) {
      Xr = Asp[b * 1025 + f];
      Xi = (f == 0 || f == 1024) ? 0.f : -Bsp[b * 1025 + f];
    } else {
      const int gg = 2048 - f;
      Xr = Asp[b * 1025 + gg];
      Xi = Bsp[b * 1025 + gg];
    }
    const int pos = __brev((unsigned)f) >> 21;
    re[pos] = Xr;
    im[pos] = Xi;
  }
  for (int s = 0; s <= 10; ++s) {
    __syncthreads();
    const int m = 1 << s;
    for (int p = 0; p < 4; ++p) {
      const int id = p * 256 + t;
      const int j = id & (m - 1);
      const int i0 = ((id >> s) << (s + 1)) + j;
      const int i1 = i0 + m;
      const int kk = (m - 1) + j;
      const float cv = twc[kk], sv = tws[kk];
      const float br = re[i1], bi = im[i1];
      const float tr = br * cv - bi * sv;
      const float ti = bi * cv + br * sv;
      const float ar = re[i0], ai = im[i0];
      re[i0] = ar + tr;
      im[i0] = ai + ti;
      re[i1] = ar - tr;
      im[i1] = ai - ti;
    }
  }
  __syncthreads();
#pragma unroll
  for (int i = 0; i < 8; ++i) {
    const int n = i * 256 + t;
    im[n] = re[n] * (1.0f / (2048.0f * 512.0f));
  }
  __syncthreads();
  for (int round = 0; round < kTopk; ++round) {
    float bv = -INFINITY;
    int bi = 0x7fffffff;
#pragma unroll
    for (int i = 0; i < 8; ++i) {
      const int n = i * 256 + t;
      const float v = im[n];
      if (v > bv || (v == bv && n < bi)) { bv = v; bi = n; }
    }
    rv[t] = bv;
    ri[t] = bi;
    __syncthreads();
    for (int s = 128; s > 0; s >>= 1) {
      if (t < s) {
        const float v2 = rv[t + s];
        const int i2 = ri[t + s];
        if (v2 > rv[t] || (v2 == rv[t] && i2 < ri[t])) { rv[t] = v2; ri[t] = i2; }
      }
      __syncthreads();
    }
    if (t == 0) {
      topv[round] = rv[0];
      topi[round] = ri[0];
      im[ri[0]] = -INFINITY;
    }
    __syncthreads();
  }
  if (t == 0) {
    const float m = topv[0];
    float sum = 0.f;
    float e[kTopk];
    for (int i = 0; i < kTopk; ++i) { e[i] = expf(topv[i] - m); sum += e[i]; }
    for (int i = 0; i < kTopk; ++i) {
      wts[b * 16 + i] = e[i] / sum;
      dly[b * 16 + i] = topi[i];
    }
  }
}

// attn_in[b,l,c] = sum_t w_t * v[b,(l+delay_t)%L,c]; 1-D grid, batch = lin%8
__global__ __launch_bounds__(256)
void agg_kernel(const u16* __restrict__ qkv, const float* __restrict__ wts,
                const int* __restrict__ dly, u16* __restrict__ out) {
  __shared__ float w[16];
  __shared__ int dl[16];
  const int lin = blockIdx.x;
  const int b = lin & 7;
  if (threadIdx.x < kTopk) {
    w[threadIdx.x] = wts[b * 16 + threadIdx.x];
    dl[threadIdx.x] = dly[b * 16 + threadIdx.x];
  }
  __syncthreads();
  const int l = (lin >> 3) * 4 + (threadIdx.x >> 6);
  const int co = (threadIdx.x & 63) * 8;
  const u16* vb = qkv + (size_t)b * kL * 1536 + 1024 + co;
  float a[8] = {0.f, 0.f, 0.f, 0.f, 0.f, 0.f, 0.f, 0.f};
  for (int t = 0; t < kTopk; ++t) {
    const int row = (l + dl[t]) & kLMask;
    float4 rv = *(const float4*)(vb + (size_t)row * 1536);
    const u16* p = (const u16*)&rv;
    const float wt = w[t];
#pragma unroll
    for (int e = 0; e < 8; ++e) a[e] += wt * b2f(p[e]);
  }
  u16 ob[8];
#pragma unroll
  for (int e = 0; e < 8; ++e) ob[e] = f2b(a[e]);
  *(float4*)(out + ((size_t)b * kL + l) * kD + co) = *(const float4*)ob;
}

// decomp, bf16 in -> bf16 out (streaming 25-tap clamped MA)
__global__ __launch_bounds__(256)
void decomp_b2b(const u16* __restrict__ X, u16* __restrict__ OB) {
  const int c = blockIdx.x * 256 + threadIdx.x;
  const int b = blockIdx.y;
  const int l0 = blockIdx.z * 64;
  const u16* base = X + (size_t)b * kL * kD + c;
  float sum = 0.f;
#pragma unroll
  for (int m = -12; m <= 12; ++m) {
    int lm = l0 + m;
    lm = lm < 0 ? 0 : (lm > kL - 1 ? kL - 1 : lm);
    sum += b2f(base[(size_t)lm * kD]);
  }
#pragma unroll 4
  for (int l = l0; l < l0 + 64; ++l) {
    const float val = b2f(base[(size_t)l * kD]);
    OB[((size_t)b * kL + l) * kD + c] = f2b(val - sum * (1.0f / 25.0f));
    const int la = l + 13 > kL - 1 ? kL - 1 : l + 13;
    const int lr = l - 12 < 0 ? 0 : l - 12;
    sum += b2f(base[(size_t)la * kD]) - b2f(base[(size_t)lr * kD]);
  }
}

// decomp, fp32 in -> fp32 out (single input; FFN2 writes the full sum)
__global__ __launch_bounds__(256)
void decomp_f2f(const float* __restrict__ X, float* __restrict__ OF) {
  const int c = blockIdx.x * 256 + threadIdx.x;
  const int b = blockIdx.y;
  const int l0 = blockIdx.z * 64;
  const float* base = X + (size_t)b * kL * kD + c;
  float sum = 0.f;
#pragma unroll
  for (int m = -12; m <= 12; ++m) {
    int lm = l0 + m;
    lm = lm < 0 ? 0 : (lm > kL - 1 ? kL - 1 : lm);
    sum += base[(size_t)lm * kD];
  }
#pragma unroll 4
  for (int l = l0; l < l0 + 64; ++l) {
    const float val = base[(size_t)l * kD];
    OF[((size_t)b * kL + l) * kD + c] = val - sum * (1.0f / 25.0f);
    const int la = l + 13 > kL - 1 ? kL - 1 : l + 13;
    const int lr = l - 12 < 0 ? 0 : l - 12;
    sum += base[(size_t)la * kD] - base[(size_t)lr * kD];
  }
}

extern "C" void kernel_launch(void* const* d_in, const int* in_sizes, int n_in,
                              void* d_out, int out_size, void* d_ws, size_t ws_size,
                              hipStream_t stream) {
  const float* x  = (const float*)d_in[0];
  const float* Wq = (const float*)d_in[1];
  const float* bq = (const float*)d_in[2];
  const float* Wk = (const float*)d_in[3];
  const float* bk = (const float*)d_in[4];
  const float* Wv = (const float*)d_in[5];
  const float* bv = (const float*)d_in[6];
  const float* Wo = (const float*)d_in[7];
  const float* bo = (const float*)d_in[8];
  const float* W1 = (const float*)d_in[9];
  const float* W2 = (const float*)d_in[10];
  float* out = (float*)d_out;

  const size_t MiB = 1u << 20;
  const size_t NBLD = (size_t)kB * kL * kD;  // 8,388,608
  char* base = (char*)d_ws;
  u16*   qkvb  = (u16*)(base);               // [0,48)
  u16*   xb    = (u16*)(base + 48 * MiB);    // [48,64) ; aggb aliases
  u16*   aggb  = xb;
  u16*   xrb   = (u16*)(base + 64 * MiB);    // [64,80)
  u16*   s1b   = (u16*)(base + 80 * MiB);    // [80,96)
  u16*   midb  = (u16*)(base + 96 * MiB);    // [96,160)
  float* s2p   = (float*)(base);             // [0,64) after qkvb/aggb dead
  u16*   Wqkvt = (u16*)(base + 160 * MiB);   // 2 MiB (incl Wot as slot 3)
  u16*   Wot   = Wqkvt + 3 * 512 * 512;
  u16*   W1t   = (u16*)(base + 162 * MiB);   // 2 MiB
  u16*   W2t   = (u16*)(base + 164 * MiB);   // 2 MiB
  float* bqkv  = (float*)(base + 166 * MiB);
  float* Asp   = bqkv + 2048;                // 8 x 1025
  float* Bsp   = Asp + kB * 1025;
  float* wtsf  = Bsp + kB * 1025;
  int*   dlyi  = (int*)(wtsf + kB * 16);
  float* pA    = (float*)(base + 167 * MiB); // 1024 x 1025 (~4 MiB)
  float* pB    = (float*)(base + 172 * MiB); // 1024 x 1025

  const dim3 blk(256);

  // fused input cast + weight prep + bias concat (one dispatch)
  prep_kernel<<<dim3(11270), blk, 0, stream>>>(
      x, Wq, Wk, Wv, Wo, W1, W2, bq, bk, bv, xb, Wqkvt, W1t, W2t, bqkv);

  // fused QKV projection -> qkvb bf16 (128^2 tiles, 128x12 = 1536 blocks)
  gemm128<0, 0, 1, 0, 0><<<dim3(1536), blk, 0, stream>>>(
      xb, Wqkvt, bqkv, nullptr, nullptr, qkvb, nullptr, 1536, 512, 512, 512, 12);

  // correlation spectra via packed FFTs
  fft_corr<<<dim3(1024), blk, 0, stream>>>(qkvb, pA, pB);
  reduceAB<<<dim3(8, 5), blk, 0, stream>>>(pA, pB, Asp, Bsp);
  ifft_topk<<<dim3(8), blk, 0, stream>>>(Asp, Bsp, wtsf, dlyi);

  // delay aggregation -> aggb bf16 ; Wo + bias + residual(x) -> xrb bf16
  agg_kernel<<<dim3(4096), blk, 0, stream>>>(qkvb, wtsf, dlyi, aggb);
  gemm128<0, 0, 1, 0, 1><<<dim3(512), blk, 0, stream>>>(
      aggb, Wot, bo, x, nullptr, xrb, nullptr, 512, 512, 512, 512, 4);

  // decomp 1 -> s1b bf16
  decomp_b2b<<<dim3(2, 8, 32), blk, 0, stream>>>(xrb, s1b);

  // FFN1: relu(s1b @ W1) -> midb bf16 (128x16 = 2048 blocks)
  gemm128<0, 1, 0, 0, 0><<<dim3(2048), blk, 0, stream>>>(
      s1b, W1t, nullptr, nullptr, nullptr, midb, nullptr, 2048, 512, 512, 512, 16);

  // FFN2: full K=2048, no split (512 blocks, NT=32) -> s2p fp32 + s1b residual
  gemm128<0, 0, 0, 1, 2><<<dim3(512), blk, 0, stream>>>(
      midb, W2t, nullptr, nullptr, s1b, nullptr, s2p, 512, 2048, 2048, 2048, 4);

  // decomp 2 over s2p -> out fp32
  decomp_f2f<<<dim3(2, 8, 32), blk, 0, stream>>>(s2p, out);
}